// Round 1
// baseline (742.950 us; speedup 1.0000x reference)
//
#include <hip/hip_runtime.h>

#define S_TOT 3872
#define C_DIM 1536
#define NHEAD 12
#define DHEAD 128
#define TT 8
#define HH 22
#define WW 22
#define NKT 61          // ceil(3872/64)  (key tiles, and ln_stats grid)
#define NQT 41          // ceil(3872/96)  (query tiles for attn)

typedef __bf16 bf16x8 __attribute__((ext_vector_type(8)));
typedef float  f32x4  __attribute__((ext_vector_type(4)));
typedef unsigned short u16x8 __attribute__((ext_vector_type(8)));

__device__ __forceinline__ float bf2f(unsigned short u) {
    unsigned int v = ((unsigned int)u) << 16;
    float f; __builtin_memcpy(&f, &v, 4); return f;
}
__device__ __forceinline__ unsigned short f2bf(float f) {
    unsigned int u; __builtin_memcpy(&u, &f, 4);
    u += 0x7fffu + ((u >> 16) & 1u);
    return (unsigned short)(u >> 16);
}
// truncation-pack two f32 -> bf16x2 dword (internal P only; 1-ulp bias ok)
__device__ __forceinline__ unsigned int pk2_trunc(float a, float b) {
    unsigned int ua, ub;
    __builtin_memcpy(&ua, &a, 4); __builtin_memcpy(&ub, &b, 4);
    return (ua >> 16) | (ub & 0xffff0000u);
}
__device__ __forceinline__ float ldin(const void* p, size_t i, int isf32) {
    if (isf32) return ((const float*)p)[i];
    return bf2f(((const unsigned short*)p)[i]);
}
__device__ __forceinline__ float fexp2(float x) {
#if __has_builtin(__builtin_amdgcn_exp2f)
    return __builtin_amdgcn_exp2f(x);
#else
    return exp2f(x);
#endif
}
__device__ __forceinline__ void async16(const void* g, void* l) {
    __builtin_amdgcn_global_load_lds(
        (const __attribute__((address_space(1))) unsigned int*)g,
        (__attribute__((address_space(3))) unsigned int*)l, 16, 0, 0);
}

// ------- dtype detector + bias/gain conversion (1 block) --------------
__global__ void detect_vecs(const unsigned short* __restrict__ x,
                            const void* p0, const void* p1, const void* p2,
                            const void* p3, const void* p4, const void* p5,
                            int* __restrict__ flag, unsigned short* __restrict__ vecs) {
    __shared__ int cnt;
    if (threadIdx.x == 0) cnt = 0;
    __syncthreads();
    int c = 0;
    for (int i = 0; i < 8; ++i) {
        unsigned short u = x[threadIdx.x * 8 + i];
        int e = (u >> 7) & 0xFF;
        if (e >= 112 && e <= 143) c++;
    }
    atomicAdd(&cnt, c);
    __syncthreads();
    int isf32 = (cnt >= 1900) ? 0 : 1;
    if (threadIdx.x == 0) *flag = isf32;
    const void* ps[6] = {p0, p1, p2, p3, p4, p5};
    for (int v = 0; v < 6; ++v)
        for (int j = threadIdx.x; j < C_DIM; j += 256)
            vecs[v * C_DIM + j] = f2bf(ldin(ps[v], j, isf32));
}

// -------- two weight matrices -> bf16, grid (1152, 2) -----------------
__global__ __launch_bounds__(256) void wconv2(const void* __restrict__ sA,
                                              const void* __restrict__ sB,
                                              const int* __restrict__ flag,
                                              unsigned short* __restrict__ dA,
                                              unsigned short* __restrict__ dB) {
    const void* src = blockIdx.y ? sB : sA;
    unsigned short* dst = blockIdx.y ? dB : dA;
    size_t i = ((size_t)blockIdx.x * 256 + threadIdx.x) * 8;
    if (*flag) {
        const float* s = (const float*)src + i;
        float4 a = *(const float4*)s, b = *(const float4*)(s + 4);
        u16x8 o;
        o[0]=f2bf(a.x); o[1]=f2bf(a.y); o[2]=f2bf(a.z); o[3]=f2bf(a.w);
        o[4]=f2bf(b.x); o[5]=f2bf(b.y); o[6]=f2bf(b.z); o[7]=f2bf(b.w);
        *(u16x8*)(dst + i) = o;
    } else {
        *(u16x8*)(dst + i) = *(const u16x8*)((const unsigned short*)src + i);
    }
}

// ---------------- LayerNorm stats: grid 61, block (64 s x 4 cg) -------
__global__ __launch_bounds__(256) void ln_stats(const void* __restrict__ x,
                                                const int* __restrict__ flag,
                                                float* __restrict__ meanb,
                                                float* __restrict__ rstdb) {
    int isf32 = *flag;
    int sl = threadIdx.x & 63, cg = threadIdx.x >> 6;
    int s = blockIdx.x * 64 + sl;
    float sum = 0.f, sumsq = 0.f;
    if (s < S_TOT) {
        for (int c = cg; c < C_DIM; c += 4) {
            float v = ldin(x, (size_t)c * S_TOT + s, isf32);
            sum += v; sumsq += v * v;
        }
    }
    __shared__ float r0[4][64], r1[4][64];
    r0[cg][sl] = sum; r1[cg][sl] = sumsq;
    __syncthreads();
    if (cg == 0 && s < S_TOT) {
        float st = r0[0][sl] + r0[1][sl] + r0[2][sl] + r0[3][sl];
        float sq = r1[0][sl] + r1[1][sl] + r1[2][sl] + r1[3][sl];
        float m = st * (1.0f / C_DIM);
        float var = sq * (1.0f / C_DIM) - m * m;
        meanb[s] = m;
        rstdb[s] = rsqrtf(var + 1e-6f);
    }
}

// ------------- Normalize + transpose (C,S) -> (S,C) bf16 --------------
__global__ __launch_bounds__(256) void ln_norm_t(const void* __restrict__ x,
                                                 const int* __restrict__ flag,
                                                 const float* __restrict__ meanb,
                                                 const float* __restrict__ rstdb,
                                                 unsigned short* __restrict__ xn) {
    int isf32 = *flag;
    __shared__ float tile[32][33];
    int s0 = blockIdx.x * 32, c0 = blockIdx.y * 32;
    int tx = threadIdx.x, ty = threadIdx.y;   // (32,8)
    for (int r = 0; r < 4; ++r) {
        int cl = ty + 8 * r;
        tile[cl][tx] = ldin(x, (size_t)(c0 + cl) * S_TOT + (s0 + tx), isf32);
    }
    __syncthreads();
    for (int r = 0; r < 4; ++r) {
        int sl = ty + 8 * r;
        int s = s0 + sl, c = c0 + tx;
        xn[(size_t)s * C_DIM + c] = f2bf((tile[tx][sl] - meanb[s]) * rstdb[s]);
    }
}

// ------- MFMA GEMM 64x128, BK=32, DMA staging; 732 blocks -------------
__global__ __launch_bounds__(256) void gemm64(const unsigned short* __restrict__ A,
                                              const unsigned short* __restrict__ W,
                                              const unsigned short* __restrict__ bias,
                                              unsigned short* __restrict__ D,
                                              int transV) {
    __shared__ __align__(16) unsigned short As[2048];   // 64 rows x 32
    __shared__ __align__(16) unsigned short Bs[4096];   // 128 rows x 32
    int m0 = blockIdx.x * 64, n0 = blockIdx.y * 128;
    int tid = threadIdx.x;
    int wave = tid >> 6, lane = tid & 63;
    int lm = lane & 15, lq = lane >> 4;
    int srow = lane >> 2, scol = (lane & 3) * 8;

    f32x4 acc[4][2];
    #pragma unroll
    for (int a = 0; a < 4; ++a)
        #pragma unroll
        for (int b = 0; b < 2; ++b) acc[a][b] = (f32x4){0.f, 0.f, 0.f, 0.f};

    for (int k0 = 0; k0 < C_DIM; k0 += 32) {
        __syncthreads();
        #pragma unroll
        for (int t = 0; t < 3; ++t) {
            int g = wave * 3 + t;   // 0..11
            if (g < 4) {
                int am = m0 + g * 16 + srow; if (am > S_TOT - 1) am = S_TOT - 1;
                async16(A + (size_t)am * C_DIM + k0 + scol, (char*)As + g * 1024);
            } else {
                int bn = n0 + (g - 4) * 16 + srow;
                async16(W + (size_t)bn * C_DIM + k0 + scol, (char*)Bs + (g - 4) * 1024);
            }
        }
        __syncthreads();
        bf16x8 af[4], bf[2];
        #pragma unroll
        for (int mb = 0; mb < 4; ++mb)
            af[mb] = *(const bf16x8*)((const char*)As + (mb * 16 + lm) * 64 + lq * 16);
        #pragma unroll
        for (int nb = 0; nb < 2; ++nb)
            bf[nb] = *(const bf16x8*)((const char*)Bs + (wave * 32 + nb * 16 + lm) * 64 + lq * 16);
        #pragma unroll
        for (int mb = 0; mb < 4; ++mb)
            #pragma unroll
            for (int nb = 0; nb < 2; ++nb)
                acc[mb][nb] = __builtin_amdgcn_mfma_f32_16x16x32_bf16(af[mb], bf[nb], acc[mb][nb], 0, 0, 0);
    }

    if (!transV) {
        #pragma unroll
        for (int mb = 0; mb < 4; ++mb)
            #pragma unroll
            for (int nb = 0; nb < 2; ++nb) {
                int gn = n0 + wave * 32 + nb * 16 + lm;
                float bv = bf2f(bias[gn]);
                #pragma unroll
                for (int r = 0; r < 4; ++r) {
                    int gm = m0 + mb * 16 + lq * 4 + r;
                    if (gm < S_TOT) D[(size_t)gm * C_DIM + gn] = f2bf(acc[mb][nb][r] + bv);
                }
            }
    } else {
        #pragma unroll
        for (int mb = 0; mb < 4; ++mb) {
            int gm0 = m0 + mb * 16 + lq * 4;
            if (gm0 >= S_TOT) continue;
            #pragma unroll
            for (int nb = 0; nb < 2; ++nb) {
                int gn = n0 + wave * 32 + nb * 16 + lm;
                float bv = bf2f(bias[gn]);
                ushort4 pk;
                pk.x = f2bf(acc[mb][nb][0] + bv);
                pk.y = f2bf(acc[mb][nb][1] + bv);
                pk.z = f2bf(acc[mb][nb][2] + bv);
                pk.w = f2bf(acc[mb][nb][3] + bv);
                *(ushort4*)(D + (size_t)gn * S_TOT + gm0) = pk;
            }
        }
    }
}

// ---------- RMSNorm + RoPE for Q and K in one launch, in-place --------
__global__ __launch_bounds__(256) void rope2(unsigned short* __restrict__ qbuf,
                                             unsigned short* __restrict__ kbuf,
                                             const unsigned short* __restrict__ gq,
                                             const unsigned short* __restrict__ gk,
                                             float qsc) {
    int s = blockIdx.x;
    unsigned short* row = (blockIdx.y ? kbuf : qbuf) + (size_t)s * C_DIM;
    const unsigned short* g = blockIdx.y ? gk : gq;
    float premul = blockIdx.y ? 1.0f : qsc;
    int tid = threadIdx.x;
    float ss = 0.f;
    for (int i = 0; i < 6; ++i) {
        float v = bf2f(row[tid + 256 * i]);
        ss += v * v;
    }
    for (int off = 32; off; off >>= 1) ss += __shfl_down(ss, off, 64);
    __shared__ float wsum[4];
    __shared__ float scale_sh;
    if ((tid & 63) == 0) wsum[tid >> 6] = ss;
    __syncthreads();
    if (tid == 0) {
        float tot = wsum[0] + wsum[1] + wsum[2] + wsum[3];
        scale_sh = rsqrtf(tot * (1.0f / C_DIM) + 1e-6f) * premul;
    }
    __syncthreads();
    float scale = scale_sh;

    int t  = s / (HH * WW);
    int rm = s % (HH * WW);
    int hh = rm / WW, ww = rm % WW;

    float e[3][2];
    int cols[3];
    for (int i = 0; i < 3; ++i) {
        int p = tid + 256 * i;
        int j = p & 63;
        int col0 = (p >> 6) * DHEAD + 2 * j;
        cols[i] = col0;
        float e0 = bf2f(row[col0])     * scale * bf2f(g[col0]);
        float e1 = bf2f(row[col0 + 1]) * scale * bf2f(g[col0 + 1]);
        float pos, fr;
        if (j < 22)       { pos = (float)t;  fr = (float)j        * (1.0f / 22.0f); }
        else if (j < 43)  { pos = (float)hh; fr = (float)(j - 22) * (1.0f / 21.0f); }
        else              { pos = (float)ww; fr = (float)(j - 43) * (1.0f / 21.0f); }
        float ang = pos * expf(fr * -9.210340371976184f);
        float c = cosf(ang), sn = sinf(ang);
        e[i][0] = e0 * c - e1 * sn;
        e[i][1] = e0 * sn + e1 * c;
    }
    for (int i = 0; i < 3; ++i) {
        row[cols[i]]     = f2bf(e[i][0]);
        row[cols[i] + 1] = f2bf(e[i][1]);
    }
}

// ---------------- MFMA flash attention v4 (S^T orientation) -----------
// S^T = K*Q^T (swap mfma args); each lane owns one q-column per q-GROUP
// (two groups of 16 q per wave -> every kf/vf LDS read feeds 2 MFMAs).
// 3 waves x 32 q = 96 q per block; grid 12*41 = 492 (busiest-CU q-work
// stays 192 q = old 3x64, so efficiency gain isn't lost to imbalance).
// PV as O^T = V^T * P^T. Strides 72 (pad 8): bank-uniform (lm+lq)%8.
// LDS 48 KiB -> 3 blocks/CU; launch_bounds(192,3) pins VGPR<=170.
__global__ __launch_bounds__(192, 3) void attn_mfma(const unsigned short* __restrict__ q,
                                                    const unsigned short* __restrict__ kp,
                                                    const unsigned short* __restrict__ vt,
                                                    unsigned short* __restrict__ o) {
    __shared__ __align__(16) unsigned char Ks[16896];      // 16 groups * 1056B
    __shared__ __align__(16) unsigned short Vs[128 * 72];  // [d][keys], pad 8
    __shared__ __align__(16) unsigned short Ps[3][32 * 72];// [wave][q32][keys]

    int h  = blockIdx.x / NQT;
    int qt = blockIdx.x % NQT;
    int q0 = qt * 96;
    int tid = threadIdx.x;
    int wave = tid >> 6, lane = tid & 63;
    int lm = lane & 15, lq = lane >> 4;

    // Q as B-operand fragments, two q-groups (lane = q-col, regs = d)
    bf16x8 qf[2][4];
    #pragma unroll
    for (int g = 0; g < 2; ++g) {
        int qr = q0 + wave * 32 + g * 16 + lm; if (qr >= S_TOT) qr = S_TOT - 1;
        const unsigned short* qptr = q + (size_t)qr * C_DIM + h * DHEAD + lq * 8;
        #pragma unroll
        for (int kc = 0; kc < 4; ++kc) qf[g][kc] = *(const bf16x8*)(qptr + kc * 32);
    }

    // K DMA constants
    int kgrow = lane >> 4;
    size_t kcol = (size_t)(h * DHEAD + (lane & 15) * 8);
    // V staging constants: 1024 16B-slots over 192 threads (5 full + 1/3)
    const unsigned short* vbase = vt + (size_t)h * DHEAD * S_TOT;
    int vds[6], kss[6];
    #pragma unroll
    for (int c = 0; c < 6; ++c) { int idx = c * 192 + tid; vds[c] = idx >> 3; kss[c] = idx & 7; }
    // K frag read offsets (bytes)
    int ksoff[4], kqoff[4];
    #pragma unroll
    for (int nt = 0; nt < 4; ++nt) ksoff[nt] = (nt * 4 + (lm >> 2)) * 1056 + (lm & 3) * 256;
    #pragma unroll
    for (int kc = 0; kc < 4; ++kc) kqoff[kc] = (kc * 4 + lq) * 16;

    f32x4 oacc[2][8];
    #pragma unroll
    for (int g = 0; g < 2; ++g)
        #pragma unroll
        for (int i = 0; i < 8; ++i) oacc[g][i] = (f32x4){0.f, 0.f, 0.f, 0.f};
    float m_run[2] = {-__builtin_inff(), -__builtin_inff()};
    float l_run[2] = {0.f, 0.f};

    for (int kt = 0; kt < NKT; ++kt) {
        int k0 = kt * 64;
        __syncthreads();               // prev tile's Ks/Vs reads complete
        // K tile DMA (16 groups of 4 rows x 128 d), 3 waves x 6 groups
        #pragma unroll
        for (int t = 0; t < 6; ++t) {
            int g = wave * 6 + t;
            if (g < 16) {
                int grow = k0 + g * 4 + kgrow; if (grow > S_TOT - 1) grow = S_TOT - 1;
                async16(kp + (size_t)grow * C_DIM + kcol, Ks + g * 1056);
            }
        }
        // V tile: [d][key] stride 72, 16B slots, coalesced 128B per 8 lanes
        #pragma unroll
        for (int c = 0; c < 5; ++c) {
            int gk = k0 + kss[c] * 8; if (gk > S_TOT - 8) gk = S_TOT - 8;
            uint4 val = *(const uint4*)(vbase + (size_t)vds[c] * S_TOT + gk);
            *(uint4*)(&Vs[vds[c] * 72 + kss[c] * 8]) = val;
        }
        if (tid < 64) {
            int gk = k0 + kss[5] * 8; if (gk > S_TOT - 8) gk = S_TOT - 8;
            uint4 val = *(const uint4*)(vbase + (size_t)vds[5] * S_TOT + gk);
            *(uint4*)(&Vs[vds[5] * 72 + kss[5] * 8]) = val;
        }
        __syncthreads();               // DMA + V loads drained, LDS visible

        // S^T[key][q]: sacc[g][nt] covers keys nt*16.., cols = q-group g
        f32x4 sacc[2][4];
        #pragma unroll
        for (int g = 0; g < 2; ++g)
            #pragma unroll
            for (int nt = 0; nt < 4; ++nt) sacc[g][nt] = (f32x4){0.f, 0.f, 0.f, 0.f};
        #pragma unroll
        for (int kc = 0; kc < 4; ++kc)
            #pragma unroll
            for (int nt = 0; nt < 4; ++nt) {
                bf16x8 kf = *(const bf16x8*)(Ks + ksoff[nt] + kqoff[kc]);
                sacc[0][nt] = __builtin_amdgcn_mfma_f32_16x16x32_bf16(kf, qf[0][kc], sacc[0][nt], 0, 0, 0);
                sacc[1][nt] = __builtin_amdgcn_mfma_f32_16x16x32_bf16(kf, qf[1][kc], sacc[1][nt], 0, 0, 0);
            }
        // mask tail keys
        if (kt == NKT - 1) {
            #pragma unroll
            for (int g = 0; g < 2; ++g)
                #pragma unroll
                for (int nt = 0; nt < 4; ++nt)
                    #pragma unroll
                    for (int r = 0; r < 4; ++r)
                        if (k0 + nt * 16 + lq * 4 + r >= S_TOT) sacc[g][nt][r] = -__builtin_inff();
        }
        // online softmax per q-group, base-2, scalar state (q = g*16+lm)
        #pragma unroll
        for (int g = 0; g < 2; ++g) {
            float rmax = sacc[g][0][0];
            #pragma unroll
            for (int nt = 0; nt < 4; ++nt)
                #pragma unroll
                for (int r = 0; r < 4; ++r) rmax = fmaxf(rmax, sacc[g][nt][r]);
            rmax = fmaxf(rmax, __shfl_xor(rmax, 16, 64));
            rmax = fmaxf(rmax, __shfl_xor(rmax, 32, 64));
            float mn = fmaxf(m_run[g], rmax);
            float alpha = fexp2(m_run[g] - mn);
            float rs = 0.f;
            #pragma unroll
            for (int nt = 0; nt < 4; ++nt)
                #pragma unroll
                for (int r = 0; r < 4; ++r) {
                    float p = fexp2(sacc[g][nt][r] - mn);
                    sacc[g][nt][r] = p;
                    rs += p;
                }
            rs += __shfl_xor(rs, 16, 64);
            rs += __shfl_xor(rs, 32, 64);
            l_run[g] = l_run[g] * alpha + rs;
            m_run[g] = mn;
            // P^T -> per-wave LDS: row q=g*16+lm, keys nt*16+lq*4..
            #pragma unroll
            for (int nt = 0; nt < 4; ++nt) {
                uint2 pk;
                pk.x = pk2_trunc(sacc[g][nt][0], sacc[g][nt][1]);
                pk.y = pk2_trunc(sacc[g][nt][2], sacc[g][nt][3]);
                *(uint2*)(&Ps[wave][(g * 16 + lm) * 72 + nt * 16 + lq * 4]) = pk;
            }
            // rescale O^T for this group
            #pragma unroll
            for (int i = 0; i < 8; ++i)
                #pragma unroll
                for (int r = 0; r < 4; ++r) oacc[g][i][r] *= alpha;
        }
        // PV: O^T[d][q] += V^T[d][key] * P^T[key][q]; each vf feeds 2 MFMAs
        #pragma unroll
        for (int kc = 0; kc < 2; ++kc) {
            bf16x8 pf0 = *(const bf16x8*)(&Ps[wave][lm * 72 + kc * 32 + lq * 8]);
            bf16x8 pf1 = *(const bf16x8*)(&Ps[wave][(16 + lm) * 72 + kc * 32 + lq * 8]);
            #pragma unroll
            for (int mt = 0; mt < 8; ++mt) {
                bf16x8 vf = *(const bf16x8*)(&Vs[(mt * 16 + lm) * 72 + kc * 32 + lq * 8]);
                oacc[0][mt] = __builtin_amdgcn_mfma_f32_16x16x32_bf16(vf, pf0, oacc[0][mt], 0, 0, 0);
                oacc[1][mt] = __builtin_amdgcn_mfma_f32_16x16x32_bf16(vf, pf1, oacc[1][mt], 0, 0, 0);
            }
        }
    }
    // epilogue: lane owns q-column per group; d runs over mt/lq/r
    #pragma unroll
    for (int g = 0; g < 2; ++g) {
        int qrow = q0 + wave * 32 + g * 16 + lm;
        if (qrow < S_TOT) {
            float inv = 1.0f / l_run[g];
            #pragma unroll
            for (int mt = 0; mt < 8; ++mt) {
                ushort4 pk;
                pk.x = f2bf(oacc[g][mt][0] * inv);
                pk.y = f2bf(oacc[g][mt][1] * inv);
                pk.z = f2bf(oacc[g][mt][2] * inv);
                pk.w = f2bf(oacc[g][mt][3] * inv);
                *(ushort4*)(o + (size_t)qrow * C_DIM + h * DHEAD + mt * 16 + lq * 4) = pk;
            }
        }
    }
}

// ------ Residual + transpose (S,C) bf16 -> (C,S) out (dual dtype) -----
__global__ __launch_bounds__(256) void resid_t(const unsigned short* __restrict__ proj,
                                               const void* __restrict__ x,
                                               const int* __restrict__ flag,
                                               void* __restrict__ out) {
    int isf32 = *flag;
    __shared__ float tile[32][33];
    int s0 = blockIdx.x * 32, c0 = blockIdx.y * 32;
    int tx = threadIdx.x, ty = threadIdx.y;   // (32,8)
    for (int r = 0; r < 4; ++r) {
        int sl = ty + 8 * r;
        tile[sl][tx] = bf2f(proj[(size_t)(s0 + sl) * C_DIM + (c0 + tx)]);
    }
    __syncthreads();
    for (int r = 0; r < 4; ++r) {
        int cl = ty + 8 * r;
        size_t idx = (size_t)(c0 + cl) * S_TOT + (s0 + tx);
        float val = ldin(x, idx, isf32) + tile[tx][cl];
        if (isf32) ((float*)out)[idx] = val;
        else       ((unsigned short*)out)[idx] = f2bf(val);
    }
}

extern "C" void kernel_launch(void* const* d_in, const int* in_sizes, int n_in,
                              void* d_out, int out_size, void* d_ws, size_t ws_size,
                              hipStream_t stream) {
    const void* x  = d_in[0];
    const void* Wq = d_in[1];
    const void* bq = d_in[2];
    const void* Wk = d_in[3];
    const void* bk = d_in[4];
    const void* Wv = d_in[5];
    const void* bv = d_in[6];
    const void* Wo = d_in[7];
    const void* bo = d_in[8];
    const void* gq = d_in[9];
    const void* gk = d_in[10];

    // ws ~45.2 MB: xn 11.9 | qb 11.9 | kb 11.9 | Wslot0+1 9.4 | small
    char* ws = (char*)d_ws;
    size_t off = 0;
    auto alloc = [&](size_t bytes) -> char* {
        char* p = ws + off;
        off += (bytes + 255) & ~(size_t)255;
        return p;
    };
    const size_t SC = (size_t)S_TOT * C_DIM;
    unsigned short* xn   = (unsigned short*)alloc(SC * 2);
    unsigned short* qb   = (unsigned short*)alloc(SC * 2);
    unsigned short* kb   = (unsigned short*)alloc(SC * 2);
    unsigned short* Ws0  = (unsigned short*)alloc((size_t)C_DIM * C_DIM * 2);
    unsigned short* Ws1  = (unsigned short*)alloc((size_t)C_DIM * C_DIM * 2);
    unsigned short* vecs = (unsigned short*)alloc((size_t)6 * C_DIM * 2);
    float* meanb         = (float*)alloc((size_t)S_TOT * 4);
    float* rstdb         = (float*)alloc((size_t)S_TOT * 4);
    int*   flag          = (int*)alloc(256);
    unsigned short* Vt   = (unsigned short*)d_out;   // [C][S] scratch in d_out
    unsigned short* ob   = xn;   // alias (xn dead after V-GEMM)
    unsigned short* proj = qb;   // alias (qb dead after attn)

    unsigned short* bq_b = vecs;
    unsigned short* bk_b = vecs + C_DIM;
    unsigned short* bv_b = vecs + 2 * C_DIM;
    unsigned short* bo_b = vecs + 3 * C_DIM;
    unsigned short* gq_b = vecs + 4 * C_DIM;
    unsigned short* gk_b = vecs + 5 * C_DIM;

    const float QSC = 0.12751745f;   // 1/sqrt(128) * log2(e)

    dim3 t328(32, 8);
    dim3 tgrid(S_TOT / 32, C_DIM / 32);             // (121, 48)
    dim3 ggrid((S_TOT + 63) / 64, C_DIM / 128);     // (61, 12)
    dim3 wgrid((C_DIM * C_DIM) / 2048, 2);          // (1152, 2)
    dim3 rgrid(S_TOT, 2);

    detect_vecs<<<1, 256, 0, stream>>>((const unsigned short*)x, bq, bk, bv, bo, gq, gk, flag, vecs);
    wconv2<<<wgrid, 256, 0, stream>>>(Wq, Wk, flag, Ws0, Ws1);
    ln_stats<<<NKT, 256, 0, stream>>>(x, flag, meanb, rstdb);
    ln_norm_t<<<tgrid, t328, 0, stream>>>(x, flag, meanb, rstdb, xn);

    gemm64<<<ggrid, 256, 0, stream>>>(xn, Ws0, bq_b, qb, 0);
    gemm64<<<ggrid, 256, 0, stream>>>(xn, Ws1, bk_b, kb, 0);
    rope2<<<rgrid, 256, 0, stream>>>(qb, kb, gq_b, gk_b, QSC);

    wconv2<<<wgrid, 256, 0, stream>>>(Wv, Wo, flag, Ws0, Ws1);  // slots free again
    gemm64<<<ggrid, 256, 0, stream>>>(xn, Ws0, bv_b, Vt, 1);

    attn_mfma<<<NHEAD * NQT, 192, 0, stream>>>(qb, kb, Vt, ob);

    gemm64<<<ggrid, 256, 0, stream>>>(ob, Ws1, bo_b, proj, 0);
    resid_t<<<tgrid, t328, 0, stream>>>(proj, x, flag, d_out);
}

// Round 2
// 651.349 us; speedup vs baseline: 1.1406x; 1.1406x over previous
//
#include <hip/hip_runtime.h>

#define S_TOT 3872
#define C_DIM 1536
#define NHEAD 12
#define DHEAD 128
#define TT 8
#define HH 22
#define WW 22
#define NKT 61          // ceil(3872/64)  key tiles / attn q tiles / ln grid
#define GMT 41          // ceil(3872/96)  gemm M tiles

typedef __bf16 bf16x8 __attribute__((ext_vector_type(8)));
typedef float  f32x4  __attribute__((ext_vector_type(4)));
typedef unsigned short u16x8 __attribute__((ext_vector_type(8)));

__device__ __forceinline__ float bf2f(unsigned short u) {
    unsigned int v = ((unsigned int)u) << 16;
    float f; __builtin_memcpy(&f, &v, 4); return f;
}
__device__ __forceinline__ unsigned short f2bf(float f) {
    unsigned int u; __builtin_memcpy(&u, &f, 4);
    u += 0x7fffu + ((u >> 16) & 1u);
    return (unsigned short)(u >> 16);
}
// truncation-pack two f32 -> bf16x2 dword (internal P only; 1-ulp bias ok)
__device__ __forceinline__ unsigned int pk2_trunc(float a, float b) {
    unsigned int ua, ub;
    __builtin_memcpy(&ua, &a, 4); __builtin_memcpy(&ub, &b, 4);
    return (ua >> 16) | (ub & 0xffff0000u);
}
__device__ __forceinline__ float ldin(const void* p, size_t i, int isf32) {
    if (isf32) return ((const float*)p)[i];
    return bf2f(((const unsigned short*)p)[i]);
}
__device__ __forceinline__ float fexp2(float x) {
#if __has_builtin(__builtin_amdgcn_exp2f)
    return __builtin_amdgcn_exp2f(x);
#else
    return exp2f(x);
#endif
}
__device__ __forceinline__ void async16(const void* g, void* l) {
    __builtin_amdgcn_global_load_lds(
        (const __attribute__((address_space(1))) unsigned int*)g,
        (__attribute__((address_space(3))) unsigned int*)l, 16, 0, 0);
}

// ------- dtype detector + bias/gain conversion (1 block) --------------
__global__ void detect_vecs(const unsigned short* __restrict__ x,
                            const void* p0, const void* p1, const void* p2,
                            const void* p3, const void* p4, const void* p5,
                            int* __restrict__ flag, unsigned short* __restrict__ vecs) {
    __shared__ int cnt;
    if (threadIdx.x == 0) cnt = 0;
    __syncthreads();
    int c = 0;
    for (int i = 0; i < 8; ++i) {
        unsigned short u = x[threadIdx.x * 8 + i];
        int e = (u >> 7) & 0xFF;
        if (e >= 112 && e <= 143) c++;
    }
    atomicAdd(&cnt, c);
    __syncthreads();
    int isf32 = (cnt >= 1900) ? 0 : 1;
    if (threadIdx.x == 0) *flag = isf32;
    const void* ps[6] = {p0, p1, p2, p3, p4, p5};
    for (int v = 0; v < 6; ++v)
        for (int j = threadIdx.x; j < C_DIM; j += 256)
            vecs[v * C_DIM + j] = f2bf(ldin(ps[v], j, isf32));
}

// -------- two weight matrices -> bf16, grid (1152, 2) -----------------
__global__ __launch_bounds__(256) void wconv2(const void* __restrict__ sA,
                                              const void* __restrict__ sB,
                                              const int* __restrict__ flag,
                                              unsigned short* __restrict__ dA,
                                              unsigned short* __restrict__ dB) {
    const void* src = blockIdx.y ? sB : sA;
    unsigned short* dst = blockIdx.y ? dB : dA;
    size_t i = ((size_t)blockIdx.x * 256 + threadIdx.x) * 8;
    if (*flag) {
        const float* s = (const float*)src + i;
        float4 a = *(const float4*)s, b = *(const float4*)(s + 4);
        u16x8 o;
        o[0]=f2bf(a.x); o[1]=f2bf(a.y); o[2]=f2bf(a.z); o[3]=f2bf(a.w);
        o[4]=f2bf(b.x); o[5]=f2bf(b.y); o[6]=f2bf(b.z); o[7]=f2bf(b.w);
        *(u16x8*)(dst + i) = o;
    } else {
        *(u16x8*)(dst + i) = *(const u16x8*)((const unsigned short*)src + i);
    }
}

// ---------------- LayerNorm stats: grid 61, block (64 s x 4 cg) -------
__global__ __launch_bounds__(256) void ln_stats(const void* __restrict__ x,
                                                const int* __restrict__ flag,
                                                float* __restrict__ meanb,
                                                float* __restrict__ rstdb) {
    int isf32 = *flag;
    int sl = threadIdx.x & 63, cg = threadIdx.x >> 6;
    int s = blockIdx.x * 64 + sl;
    float sum = 0.f, sumsq = 0.f;
    if (s < S_TOT) {
        for (int c = cg; c < C_DIM; c += 4) {
            float v = ldin(x, (size_t)c * S_TOT + s, isf32);
            sum += v; sumsq += v * v;
        }
    }
    __shared__ float r0[4][64], r1[4][64];
    r0[cg][sl] = sum; r1[cg][sl] = sumsq;
    __syncthreads();
    if (cg == 0 && s < S_TOT) {
        float st = r0[0][sl] + r0[1][sl] + r0[2][sl] + r0[3][sl];
        float sq = r1[0][sl] + r1[1][sl] + r1[2][sl] + r1[3][sl];
        float m = st * (1.0f / C_DIM);
        float var = sq * (1.0f / C_DIM) - m * m;
        meanb[s] = m;
        rstdb[s] = rsqrtf(var + 1e-6f);
    }
}

// ------------- Normalize + transpose (C,S) -> (S,C) bf16 --------------
__global__ __launch_bounds__(256) void ln_norm_t(const void* __restrict__ x,
                                                 const int* __restrict__ flag,
                                                 const float* __restrict__ meanb,
                                                 const float* __restrict__ rstdb,
                                                 unsigned short* __restrict__ xn) {
    int isf32 = *flag;
    __shared__ float tile[32][33];
    int s0 = blockIdx.x * 32, c0 = blockIdx.y * 32;
    int tx = threadIdx.x, ty = threadIdx.y;   // (32,8)
    for (int r = 0; r < 4; ++r) {
        int cl = ty + 8 * r;
        tile[cl][tx] = ldin(x, (size_t)(c0 + cl) * S_TOT + (s0 + tx), isf32);
    }
    __syncthreads();
    for (int r = 0; r < 4; ++r) {
        int sl = ty + 8 * r;
        int s = s0 + sl, c = c0 + tx;
        xn[(size_t)s * C_DIM + c] = f2bf((tile[tx][sl] - meanb[s]) * rstdb[s]);
    }
}

// ------- MFMA GEMM 96x128, BK=64, gload_lds + xor-swz LDS; 492 blocks -
// Per wave per K-step: 24 MFMA / 2 barriers (vs 8 in old 64x128 BK=32);
// 24 K-steps. Grid 41x12=492 -> 1.92 blocks/CU (96-tile for load balance).
// Swizzle: LDS row stride 128B would be 16-way conflicted; read byte
// ^= (row&7)<<4, write side pre-swizzles the GLOBAL column (rule #21).
__global__ __launch_bounds__(256) void gemm96(const unsigned short* __restrict__ A,
                                              const unsigned short* __restrict__ W,
                                              const unsigned short* __restrict__ bias,
                                              unsigned short* __restrict__ D,
                                              int transV) {
    __shared__ __align__(16) unsigned char As[12288];   // 96 rows x 64k, swz
    __shared__ __align__(16) unsigned char Bs[16384];   // 128 rows x 64k, swz
    int m0 = blockIdx.x * 96, n0 = blockIdx.y * 128;
    int tid = threadIdx.x;
    int wave = tid >> 6, lane = tid & 63;
    int lm = lane & 15, lq = lane >> 4;
    int r8 = lane >> 3;                    // row within 8-row DMA group
    int csw = ((lane & 7) ^ r8) * 8;       // pre-swizzled source col (ushort)
    int fxor = (lm & 7) << 4;              // read-side xor (row&7 = lm&7)

    f32x4 acc[6][2];
    #pragma unroll
    for (int a = 0; a < 6; ++a)
        #pragma unroll
        for (int b = 0; b < 2; ++b) acc[a][b] = (f32x4){0.f, 0.f, 0.f, 0.f};

    for (int k0 = 0; k0 < C_DIM; k0 += 64) {
        __syncthreads();
        // 28 groups of 1KB (A:12, B:16), 7 per wave
        #pragma unroll
        for (int t = 0; t < 7; ++t) {
            int g = wave * 7 + t;          // 0..27
            if (g < 12) {
                int am = m0 + g * 8 + r8; if (am > S_TOT - 1) am = S_TOT - 1;
                async16(A + (size_t)am * C_DIM + k0 + csw, As + g * 1024);
            } else {
                int bn = n0 + (g - 12) * 8 + r8;
                async16(W + (size_t)bn * C_DIM + k0 + csw, Bs + (g - 12) * 1024);
            }
        }
        __syncthreads();
        #pragma unroll
        for (int ks = 0; ks < 2; ++ks) {
            bf16x8 af[6], bf[2];
            #pragma unroll
            for (int mb = 0; mb < 6; ++mb)
                af[mb] = *(const bf16x8*)(As + ((((mb * 16 + lm) * 128) + ks * 64 + lq * 16) ^ fxor));
            #pragma unroll
            for (int nb = 0; nb < 2; ++nb)
                bf[nb] = *(const bf16x8*)(Bs + ((((wave * 32 + nb * 16 + lm) * 128) + ks * 64 + lq * 16) ^ fxor));
            #pragma unroll
            for (int mb = 0; mb < 6; ++mb)
                #pragma unroll
                for (int nb = 0; nb < 2; ++nb)
                    acc[mb][nb] = __builtin_amdgcn_mfma_f32_16x16x32_bf16(af[mb], bf[nb], acc[mb][nb], 0, 0, 0);
        }
    }

    if (!transV) {
        #pragma unroll
        for (int mb = 0; mb < 6; ++mb)
            #pragma unroll
            for (int nb = 0; nb < 2; ++nb) {
                int gn = n0 + wave * 32 + nb * 16 + lm;
                float bv = bf2f(bias[gn]);
                #pragma unroll
                for (int r = 0; r < 4; ++r) {
                    int gm = m0 + mb * 16 + lq * 4 + r;
                    if (gm < S_TOT) D[(size_t)gm * C_DIM + gn] = f2bf(acc[mb][nb][r] + bv);
                }
            }
    } else {
        #pragma unroll
        for (int mb = 0; mb < 6; ++mb) {
            int gm0 = m0 + mb * 16 + lq * 4;
            if (gm0 >= S_TOT) continue;
            #pragma unroll
            for (int nb = 0; nb < 2; ++nb) {
                int gn = n0 + wave * 32 + nb * 16 + lm;
                float bv = bf2f(bias[gn]);
                ushort4 pk;
                pk.x = f2bf(acc[mb][nb][0] + bv);
                pk.y = f2bf(acc[mb][nb][1] + bv);
                pk.z = f2bf(acc[mb][nb][2] + bv);
                pk.w = f2bf(acc[mb][nb][3] + bv);
                *(ushort4*)(D + (size_t)gn * S_TOT + gm0) = pk;
            }
        }
    }
}

// ---------- RMSNorm + RoPE for Q and K in one launch, in-place --------
__global__ __launch_bounds__(256) void rope2(unsigned short* __restrict__ qbuf,
                                             unsigned short* __restrict__ kbuf,
                                             const unsigned short* __restrict__ gq,
                                             const unsigned short* __restrict__ gk,
                                             float qsc) {
    int s = blockIdx.x;
    unsigned short* row = (blockIdx.y ? kbuf : qbuf) + (size_t)s * C_DIM;
    const unsigned short* g = blockIdx.y ? gk : gq;
    float premul = blockIdx.y ? 1.0f : qsc;
    int tid = threadIdx.x;
    float ss = 0.f;
    for (int i = 0; i < 6; ++i) {
        float v = bf2f(row[tid + 256 * i]);
        ss += v * v;
    }
    for (int off = 32; off; off >>= 1) ss += __shfl_down(ss, off, 64);
    __shared__ float wsum[4];
    __shared__ float scale_sh;
    if ((tid & 63) == 0) wsum[tid >> 6] = ss;
    __syncthreads();
    if (tid == 0) {
        float tot = wsum[0] + wsum[1] + wsum[2] + wsum[3];
        scale_sh = rsqrtf(tot * (1.0f / C_DIM) + 1e-6f) * premul;
    }
    __syncthreads();
    float scale = scale_sh;

    int t  = s / (HH * WW);
    int rm = s % (HH * WW);
    int hh = rm / WW, ww = rm % WW;

    float e[3][2];
    int cols[3];
    for (int i = 0; i < 3; ++i) {
        int p = tid + 256 * i;
        int j = p & 63;
        int col0 = (p >> 6) * DHEAD + 2 * j;
        cols[i] = col0;
        float e0 = bf2f(row[col0])     * scale * bf2f(g[col0]);
        float e1 = bf2f(row[col0 + 1]) * scale * bf2f(g[col0 + 1]);
        float pos, fr;
        if (j < 22)       { pos = (float)t;  fr = (float)j        * (1.0f / 22.0f); }
        else if (j < 43)  { pos = (float)hh; fr = (float)(j - 22) * (1.0f / 21.0f); }
        else              { pos = (float)ww; fr = (float)(j - 43) * (1.0f / 21.0f); }
        float ang = pos * expf(fr * -9.210340371976184f);
        float c = cosf(ang), sn = sinf(ang);
        e[i][0] = e0 * c - e1 * sn;
        e[i][1] = e0 * sn + e1 * c;
    }
    for (int i = 0; i < 3; ++i) {
        row[cols[i]]     = f2bf(e[i][0]);
        row[cols[i] + 1] = f2bf(e[i][1]);
    }
}

// ---------------- MFMA flash attention v5 (round-0 structure) ---------
// Back to 4 waves x 16q (732 blocks, all co-resident). Deltas vs v3:
//  - V staged via global_load_lds (no VALU reg round-trip); forces
//    unpadded [d][64key] layout -> xor-swz byte^=(row&7)<<4, global
//    source pre-swizzled (rule #21). Same swizzle family for K and P.
//  - s_setprio(1) around QK and PV MFMA clusters (T5, +4-7% attn).
//  - defer-max (T13): skip O-rescale when __all(rmax - m <= 8).
// LDS 16K+16K+8K = 40960B.
__global__ __launch_bounds__(256) void attn_mfma(const unsigned short* __restrict__ q,
                                                 const unsigned short* __restrict__ kp,
                                                 const unsigned short* __restrict__ vt,
                                                 unsigned short* __restrict__ o) {
    __shared__ __align__(16) unsigned char Ks[16384];  // 16 grp x 4key x 256B (swz)
    __shared__ __align__(16) unsigned char Vs[16384];  // 128 d x 128B keys (swz)
    __shared__ __align__(16) unsigned char Ps[8192];   // 4 waves x 16q x 128B (swz)

    int h  = blockIdx.x / NKT;
    int qt = blockIdx.x % NKT;
    int q0 = qt * 64;
    int tid = threadIdx.x;
    int wave = tid >> 6, lane = tid & 63;
    int lm = lane & 15, lq = lane >> 4;

    // Q as B-operand fragments (lane = q-col, regs = d); pre-scaled by qsc
    bf16x8 qf[4];
    {
        int qr = q0 + wave * 16 + lm; if (qr >= S_TOT) qr = S_TOT - 1;
        const unsigned short* qptr = q + (size_t)qr * C_DIM + h * DHEAD + lq * 8;
        #pragma unroll
        for (int kc = 0; kc < 4; ++kc) qf[kc] = *(const bf16x8*)(qptr + kc * 32);
    }

    // K DMA: group = 4 keys x 128d (1KB); lane -> key lane>>4, d-col swz by
    // (key&7) = parity*4 + keyrow; parity = t&1 (g = wave*4+t, wave*4 even)
    int krow = lane >> 4;
    int kcolA = ((lane & 15) ^ krow) * 8;
    int kcolB = ((lane & 15) ^ (4 + krow)) * 8;
    // V DMA: group = 8 d-rows x 64 keys (1KB); lane -> d lane>>3, key-slot swz
    int vr8 = lane >> 3;
    int vslot = (lane & 7) ^ vr8;

    int sxor = (lm & 7) << 4;            // read-side xor (K row&7 = V row&7 = P row&7 = lm&7)
    int ksoff[4], kqoff[4];
    #pragma unroll
    for (int nt = 0; nt < 4; ++nt) ksoff[nt] = (nt * 4 + (lm >> 2)) * 1024 + (lm & 3) * 256;
    #pragma unroll
    for (int kc = 0; kc < 4; ++kc) kqoff[kc] = (kc * 4 + lq) * 16;

    f32x4 oacc[8];
    #pragma unroll
    for (int i = 0; i < 8; ++i) oacc[i] = (f32x4){0.f, 0.f, 0.f, 0.f};
    float m_run = -__builtin_inff(), l_run = 0.f;   // scalar: one q per lane

    for (int kt = 0; kt < NKT; ++kt) {
        int k0 = kt * 64;
        __syncthreads();               // prev tile's Ks/Vs/Ps reads complete
        // K tile DMA: 4 groups per wave
        #pragma unroll
        for (int t = 0; t < 4; ++t) {
            int g = wave * 4 + t;
            int grow = k0 + g * 4 + krow; if (grow > S_TOT - 1) grow = S_TOT - 1;
            async16(kp + (size_t)grow * C_DIM + h * DHEAD + ((t & 1) ? kcolB : kcolA),
                    Ks + g * 1024);
        }
        // V tile DMA: 4 groups per wave; clamped lanes only hit invalid keys
        #pragma unroll
        for (int t = 0; t < 4; ++t) {
            int g = wave * 4 + t;
            int vcol = k0 + vslot * 8; if (vcol > S_TOT - 8) vcol = S_TOT - 8;
            async16(vt + (size_t)(h * DHEAD + g * 8 + vr8) * S_TOT + vcol,
                    Vs + g * 1024);
        }
        __syncthreads();               // DMA drained, LDS visible

        // S^T[key][q]: sacc[nt] covers keys nt*16.., cols = q
        f32x4 sacc[4];
        #pragma unroll
        for (int nt = 0; nt < 4; ++nt) sacc[nt] = (f32x4){0.f, 0.f, 0.f, 0.f};
        __builtin_amdgcn_s_setprio(1);
        #pragma unroll
        for (int kc = 0; kc < 4; ++kc)
            #pragma unroll
            for (int nt = 0; nt < 4; ++nt) {
                bf16x8 kf = *(const bf16x8*)(Ks + ((ksoff[nt] + kqoff[kc]) ^ sxor));
                sacc[nt] = __builtin_amdgcn_mfma_f32_16x16x32_bf16(kf, qf[kc], sacc[nt], 0, 0, 0);
            }
        __builtin_amdgcn_s_setprio(0);
        // mask tail keys
        if (kt == NKT - 1) {
            #pragma unroll
            for (int nt = 0; nt < 4; ++nt)
                #pragma unroll
                for (int r = 0; r < 4; ++r)
                    if (k0 + nt * 16 + lq * 4 + r >= S_TOT) sacc[nt][r] = -__builtin_inff();
        }
        // online softmax, base-2, scalar state (q = lm), defer-max (T13)
        float rmax = sacc[0][0];
        #pragma unroll
        for (int nt = 0; nt < 4; ++nt)
            #pragma unroll
            for (int r = 0; r < 4; ++r) rmax = fmaxf(rmax, sacc[nt][r]);
        rmax = fmaxf(rmax, __shfl_xor(rmax, 16, 64));
        rmax = fmaxf(rmax, __shfl_xor(rmax, 32, 64));
        int defer = __all(rmax - m_run <= 8.0f);
        if (!defer) {
            float mn = fmaxf(m_run, rmax);
            float alpha = fexp2(m_run - mn);
            l_run *= alpha;
            #pragma unroll
            for (int i = 0; i < 8; ++i)
                #pragma unroll
                for (int r = 0; r < 4; ++r) oacc[i][r] *= alpha;
            m_run = mn;
        }
        float rs = 0.f;
        #pragma unroll
        for (int nt = 0; nt < 4; ++nt)
            #pragma unroll
            for (int r = 0; r < 4; ++r) {
                float p = fexp2(sacc[nt][r] - m_run);
                sacc[nt][r] = p;
                rs += p;
            }
        rs += __shfl_xor(rs, 16, 64);
        rs += __shfl_xor(rs, 32, 64);
        l_run += rs;
        // P^T -> per-wave LDS (swz): row q=lm, keys nt*16+lq*4..
        #pragma unroll
        for (int nt = 0; nt < 4; ++nt) {
            uint2 pk;
            pk.x = pk2_trunc(sacc[nt][0], sacc[nt][1]);
            pk.y = pk2_trunc(sacc[nt][2], sacc[nt][3]);
            *(uint2*)(Ps + ((wave * 2048 + lm * 128 + nt * 32 + lq * 8) ^ sxor)) = pk;
        }
        // PV: O^T[d][q] += V^T[d][key] * P^T[key][q]
        __builtin_amdgcn_s_setprio(1);
        #pragma unroll
        for (int kc = 0; kc < 2; ++kc) {
            bf16x8 pf = *(const bf16x8*)(Ps + ((wave * 2048 + lm * 128 + kc * 64 + lq * 16) ^ sxor));
            #pragma unroll
            for (int mt = 0; mt < 8; ++mt) {
                bf16x8 vf = *(const bf16x8*)(Vs + ((((mt * 16 + lm) * 128) + kc * 64 + lq * 16) ^ sxor));
                oacc[mt] = __builtin_amdgcn_mfma_f32_16x16x32_bf16(vf, pf, oacc[mt], 0, 0, 0);
            }
        }
        __builtin_amdgcn_s_setprio(0);
    }
    // epilogue: lane owns q-column; d runs over mt/lq/r -> ushort4 stores
    int qrow = q0 + wave * 16 + lm;
    if (qrow < S_TOT) {
        float inv = 1.0f / l_run;
        #pragma unroll
        for (int mt = 0; mt < 8; ++mt) {
            ushort4 pk;
            pk.x = f2bf(oacc[mt][0] * inv);
            pk.y = f2bf(oacc[mt][1] * inv);
            pk.z = f2bf(oacc[mt][2] * inv);
            pk.w = f2bf(oacc[mt][3] * inv);
            *(ushort4*)(o + (size_t)qrow * C_DIM + h * DHEAD + mt * 16 + lq * 4) = pk;
        }
    }
}

// ------ Residual + transpose (S,C) bf16 -> (C,S) out (dual dtype) -----
__global__ __launch_bounds__(256) void resid_t(const unsigned short* __restrict__ proj,
                                               const void* __restrict__ x,
                                               const int* __restrict__ flag,
                                               void* __restrict__ out) {
    int isf32 = *flag;
    __shared__ float tile[32][33];
    int s0 = blockIdx.x * 32, c0 = blockIdx.y * 32;
    int tx = threadIdx.x, ty = threadIdx.y;   // (32,8)
    for (int r = 0; r < 4; ++r) {
        int sl = ty + 8 * r;
        tile[sl][tx] = bf2f(proj[(size_t)(s0 + sl) * C_DIM + (c0 + tx)]);
    }
    __syncthreads();
    for (int r = 0; r < 4; ++r) {
        int cl = ty + 8 * r;
        size_t idx = (size_t)(c0 + cl) * S_TOT + (s0 + tx);
        float val = ldin(x, idx, isf32) + tile[tx][cl];
        if (isf32) ((float*)out)[idx] = val;
        else       ((unsigned short*)out)[idx] = f2bf(val);
    }
}

extern "C" void kernel_launch(void* const* d_in, const int* in_sizes, int n_in,
                              void* d_out, int out_size, void* d_ws, size_t ws_size,
                              hipStream_t stream) {
    const void* x  = d_in[0];
    const void* Wq = d_in[1];
    const void* bq = d_in[2];
    const void* Wk = d_in[3];
    const void* bk = d_in[4];
    const void* Wv = d_in[5];
    const void* bv = d_in[6];
    const void* Wo = d_in[7];
    const void* bo = d_in[8];
    const void* gq = d_in[9];
    const void* gk = d_in[10];

    // ws ~45.2 MB: xn 11.9 | qb 11.9 | kb 11.9 | Wslot0+1 9.4 | small
    char* ws = (char*)d_ws;
    size_t off = 0;
    auto alloc = [&](size_t bytes) -> char* {
        char* p = ws + off;
        off += (bytes + 255) & ~(size_t)255;
        return p;
    };
    const size_t SC = (size_t)S_TOT * C_DIM;
    unsigned short* xn   = (unsigned short*)alloc(SC * 2);
    unsigned short* qb   = (unsigned short*)alloc(SC * 2);
    unsigned short* kb   = (unsigned short*)alloc(SC * 2);
    unsigned short* Ws0  = (unsigned short*)alloc((size_t)C_DIM * C_DIM * 2);
    unsigned short* Ws1  = (unsigned short*)alloc((size_t)C_DIM * C_DIM * 2);
    unsigned short* vecs = (unsigned short*)alloc((size_t)6 * C_DIM * 2);
    float* meanb         = (float*)alloc((size_t)S_TOT * 4);
    float* rstdb         = (float*)alloc((size_t)S_TOT * 4);
    int*   flag          = (int*)alloc(256);
    unsigned short* Vt   = (unsigned short*)d_out;   // [C][S] scratch in d_out
    unsigned short* ob   = xn;   // alias (xn dead after V-GEMM)
    unsigned short* proj = qb;   // alias (qb dead after attn)

    unsigned short* bq_b = vecs;
    unsigned short* bk_b = vecs + C_DIM;
    unsigned short* bv_b = vecs + 2 * C_DIM;
    unsigned short* bo_b = vecs + 3 * C_DIM;
    unsigned short* gq_b = vecs + 4 * C_DIM;
    unsigned short* gk_b = vecs + 5 * C_DIM;

    const float QSC = 0.12751745f;   // 1/sqrt(128) * log2(e)

    dim3 t328(32, 8);
    dim3 tgrid(S_TOT / 32, C_DIM / 32);             // (121, 48)
    dim3 ggrid(GMT, C_DIM / 128);                   // (41, 12)
    dim3 wgrid((C_DIM * C_DIM) / 2048, 2);          // (1152, 2)
    dim3 rgrid(S_TOT, 2);

    detect_vecs<<<1, 256, 0, stream>>>((const unsigned short*)x, bq, bk, bv, bo, gq, gk, flag, vecs);
    wconv2<<<wgrid, 256, 0, stream>>>(Wq, Wk, flag, Ws0, Ws1);
    ln_stats<<<NKT, 256, 0, stream>>>(x, flag, meanb, rstdb);
    ln_norm_t<<<tgrid, t328, 0, stream>>>(x, flag, meanb, rstdb, xn);

    gemm96<<<ggrid, 256, 0, stream>>>(xn, Ws0, bq_b, qb, 0);
    gemm96<<<ggrid, 256, 0, stream>>>(xn, Ws1, bk_b, kb, 0);
    rope2<<<rgrid, 256, 0, stream>>>(qb, kb, gq_b, gk_b, QSC);

    wconv2<<<wgrid, 256, 0, stream>>>(Wv, Wo, flag, Ws0, Ws1);  // slots free again
    gemm96<<<ggrid, 256, 0, stream>>>(xn, Ws0, bv_b, Vt, 1);

    attn_mfma<<<NHEAD * NKT, 256, 0, stream>>>(qb, kb, Vt, ob);

    gemm96<<<ggrid, 256, 0, stream>>>(ob, Ws1, bo_b, proj, 0);
    resid_t<<<tgrid, t328, 0, stream>>>(proj, x, flag, d_out);
}